// Round 1
// baseline (713.782 us; speedup 1.0000x reference)
//
#include <hip/hip_runtime.h>
#include <stdint.h>

#define B_  4
#define T_  2048
#define C_  1024
#define H_  16
#define HD_ 64
#define M_  (B_*T_)   // 8192

typedef __attribute__((ext_vector_type(8))) __bf16 bf16x8;
typedef __attribute__((ext_vector_type(4))) float f32x4;
typedef __attribute__((ext_vector_type(4))) unsigned int u32x4;

__device__ __forceinline__ unsigned short f2bf(float f) {
    union { float f; unsigned int u; } v; v.f = f;
    unsigned int r = v.u + 0x7fffu + ((v.u >> 16) & 1u);   // RNE
    return (unsigned short)(r >> 16);
}
__device__ __forceinline__ unsigned int pack2(float a, float b) {
    return (unsigned int)f2bf(a) | ((unsigned int)f2bf(b) << 16);
}

// ---------------- f32 -> bf16 convert (x) ----------------
__global__ __launch_bounds__(256) void k_cvt_x(const float* __restrict__ x,
                                               unsigned short* __restrict__ xb, int n8) {
    int i = blockIdx.x * blockDim.x + threadIdx.x;
    if (i >= n8) return;
    const float4* p = (const float4*)x + (size_t)i * 2;
    float4 a = p[0], b = p[1];
    u32x4 o = { pack2(a.x, a.y), pack2(a.z, a.w), pack2(b.x, b.y), pack2(b.z, b.w) };
    *(u32x4*)(xb + (size_t)i * 8) = o;
}

// ------------- transpose+convert weights: src[K][N] f32 -> dst[N][K] bf16 -------------
__global__ __launch_bounds__(256) void k_transpose_cvt(const float* __restrict__ src,
                                                       unsigned short* __restrict__ dst,
                                                       int rows, int cols) {
    __shared__ float tile[32][33];
    int c0 = blockIdx.x * 32, r0 = blockIdx.y * 32;
    int tx = threadIdx.x, ty = threadIdx.y;   // (32,8)
    for (int i = 0; i < 4; i++)
        tile[ty + i * 8][tx] = src[(size_t)(r0 + ty + i * 8) * cols + c0 + tx];
    __syncthreads();
    for (int i = 0; i < 4; i++)
        dst[(size_t)(c0 + ty + i * 8) * rows + r0 + tx] = f2bf(tile[tx][ty + i * 8]);
}

// ---------------- GEMM: out = A[M][1024] @ Bt[N][1024]^T (+bias) ----------------
// MODE 0: N=3072 fused QKV; scatter to q[B,H,T,hd], k[B,H,T,hd], vt[B,H,hd,T] (bf16)
// MODE 1: N=1024; out f32 [M][1024] + bias
template<int MODE>
__global__ __launch_bounds__(256) void k_gemm(
    const unsigned short* __restrict__ A,
    const unsigned short* __restrict__ Bt,
    const float* __restrict__ bias0, const float* __restrict__ bias1,
    const float* __restrict__ bias2,
    unsigned short* __restrict__ qo, unsigned short* __restrict__ ko,
    unsigned short* __restrict__ vto, float* __restrict__ outf)
{
    const int K = 1024;
    __shared__ unsigned short As[64][40];
    __shared__ unsigned short Bs[64][40];
    int m0 = blockIdx.x * 64, n0 = blockIdx.y * 64;
    int t = threadIdx.x;
    int w = t >> 6, l = t & 63;
    int wm = w >> 1, wn = w & 1;
    int lg = l >> 4, lr = l & 15;

    f32x4 zf = {0.f, 0.f, 0.f, 0.f};
    f32x4 acc[2][2];
    for (int i = 0; i < 2; i++) for (int j = 0; j < 2; j++) acc[i][j] = zf;

    int srow = t >> 2, scol = (t & 3) * 8;
    for (int k0 = 0; k0 < K; k0 += 32) {
        u32x4 av = *(const u32x4*)(A  + (size_t)(m0 + srow) * K + k0 + scol);
        u32x4 bv = *(const u32x4*)(Bt + (size_t)(n0 + srow) * K + k0 + scol);
        __syncthreads();
        *(u32x4*)(&As[srow][scol]) = av;
        *(u32x4*)(&Bs[srow][scol]) = bv;
        __syncthreads();
        bf16x8 af[2], bfr[2];
        for (int i = 0; i < 2; i++) {
            af[i]  = *(const bf16x8*)(&As[wm * 32 + i * 16 + lr][lg * 8]);
            bfr[i] = *(const bf16x8*)(&Bs[wn * 32 + i * 16 + lr][lg * 8]);
        }
        for (int i = 0; i < 2; i++)
            for (int j = 0; j < 2; j++)
                acc[i][j] = __builtin_amdgcn_mfma_f32_16x16x32_bf16(af[i], bfr[j], acc[i][j], 0, 0, 0);
    }

    for (int i = 0; i < 2; i++) for (int j = 0; j < 2; j++) {
        int mrow = m0 + wm * 32 + i * 16 + lg * 4;
        int ncol = n0 + wn * 32 + j * 16 + lr;
        if (MODE == 0) {
            int sel = ncol >> 10, nc = ncol & 1023;
            int hh = nc >> 6, dd = nc & 63;
            const float* bp = (sel == 0) ? bias0 : (sel == 1) ? bias1 : bias2;
            float bvv = bp[nc];
            for (int r = 0; r < 4; r++) {
                int mm = mrow + r;
                int bb = mm >> 11, tt = mm & (T_ - 1);
                unsigned short hv = f2bf(acc[i][j][r] + bvv);
                if (sel == 0)      qo[((size_t)((bb * H_ + hh) * T_) + tt) * HD_ + dd] = hv;
                else if (sel == 1) ko[((size_t)((bb * H_ + hh) * T_) + tt) * HD_ + dd] = hv;
                else               vto[((size_t)((bb * H_ + hh) * HD_) + dd) * T_ + tt] = hv;
            }
        } else {
            float bvv = bias0[ncol];
            for (int r = 0; r < 4; r++)
                outf[(size_t)(mrow + r) * C_ + ncol] = acc[i][j][r] + bvv;
        }
    }
}

// ---------------- causal flash attention ----------------
// grid (T/64, B*H), block 256. wave w handles q rows qbase..qbase+15.
__global__ __launch_bounds__(256) void k_attn(
    const unsigned short* __restrict__ qb,
    const unsigned short* __restrict__ kb,
    const unsigned short* __restrict__ vtb,
    unsigned short* __restrict__ yb)
{
    __shared__ unsigned short plds[4][16][40];
    int bh = blockIdx.y;
    int h = bh & (H_ - 1), b = bh >> 4;
    int t = threadIdx.x, w = t >> 6, l = t & 63;
    int lg = l >> 4, lr = l & 15;
    int qbase = blockIdx.x * 64 + w * 16;

    const unsigned short* qp = qb  + (size_t)bh * T_ * HD_;
    const unsigned short* kp = kb  + (size_t)bh * T_ * HD_;
    const unsigned short* vp = vtb + (size_t)bh * HD_ * T_;

    bf16x8 qf[2];
    qf[0] = *(const bf16x8*)(qp + (size_t)(qbase + lr) * HD_ + lg * 8);
    qf[1] = *(const bf16x8*)(qp + (size_t)(qbase + lr) * HD_ + 32 + lg * 8);

    f32x4 zf = {0.f, 0.f, 0.f, 0.f};
    f32x4 o[4];
    for (int dt = 0; dt < 4; dt++) o[dt] = zf;
    float mi[4], li[4];
    for (int r = 0; r < 4; r++) { mi[r] = -1e30f; li[r] = 0.f; }

    int qmax = qbase + 15;
    for (int j0 = 0; j0 <= qmax; j0 += 32) {
        f32x4 s[2] = {zf, zf};
        for (int n = 0; n < 2; n++) {
            bf16x8 kf0 = *(const bf16x8*)(kp + (size_t)(j0 + n * 16 + lr) * HD_ + lg * 8);
            bf16x8 kf1 = *(const bf16x8*)(kp + (size_t)(j0 + n * 16 + lr) * HD_ + 32 + lg * 8);
            s[n] = __builtin_amdgcn_mfma_f32_16x16x32_bf16(qf[0], kf0, s[n], 0, 0, 0);
            s[n] = __builtin_amdgcn_mfma_f32_16x16x32_bf16(qf[1], kf1, s[n], 0, 0, 0);
        }
        float pv[2][4], tmax[4];
        for (int r = 0; r < 4; r++) {
            int qrow = qbase + lg * 4 + r;
            float v0 = (j0 + lr      <= qrow) ? s[0][r] * 0.125f : -1e30f;
            float v1 = (j0 + 16 + lr <= qrow) ? s[1][r] * 0.125f : -1e30f;
            pv[0][r] = v0; pv[1][r] = v1;
            tmax[r] = fmaxf(v0, v1);
        }
        for (int mk = 1; mk < 16; mk <<= 1)
            for (int r = 0; r < 4; r++)
                tmax[r] = fmaxf(tmax[r], __shfl_xor(tmax[r], mk, 16));
        float fac[4], rs[4];
        for (int r = 0; r < 4; r++) {
            float mn = fmaxf(mi[r], tmax[r]);
            fac[r] = __expf(mi[r] - mn);
            mi[r] = mn;
            float p0 = __expf(pv[0][r] - mn);
            float p1 = __expf(pv[1][r] - mn);
            pv[0][r] = p0; pv[1][r] = p1;
            rs[r] = p0 + p1;
        }
        for (int mk = 1; mk < 16; mk <<= 1)
            for (int r = 0; r < 4; r++)
                rs[r] += __shfl_xor(rs[r], mk, 16);
        for (int r = 0; r < 4; r++) {
            li[r] = li[r] * fac[r] + rs[r];
            for (int dt = 0; dt < 4; dt++) o[dt][r] *= fac[r];
        }
        // P -> LDS (transpose to A-frag layout), per-wave private region
        for (int n = 0; n < 2; n++)
            for (int r = 0; r < 4; r++)
                plds[w][lg * 4 + r][n * 16 + lr] = f2bf(pv[n][r]);
        asm volatile("s_waitcnt lgkmcnt(0)" ::: "memory");
        bf16x8 pf = *(const bf16x8*)(&plds[w][lr][lg * 8]);
        for (int dt = 0; dt < 4; dt++) {
            bf16x8 vf = *(const bf16x8*)(vp + (size_t)(dt * 16 + lr) * T_ + j0 + lg * 8);
            o[dt] = __builtin_amdgcn_mfma_f32_16x16x32_bf16(pf, vf, o[dt], 0, 0, 0);
        }
    }

    for (int r = 0; r < 4; r++) {
        float inv = 1.f / li[r];
        int tt = qbase + lg * 4 + r;
        for (int dt = 0; dt < 4; dt++)
            yb[((size_t)(b * T_ + tt)) * C_ + h * HD_ + dt * 16 + lr] = f2bf(o[dt][r] * inv);
    }
}

// ---------------- launcher ----------------
extern "C" void kernel_launch(void* const* d_in, const int* in_sizes, int n_in,
                              void* d_out, int out_size, void* d_ws, size_t ws_size,
                              hipStream_t stream) {
    const float* x  = (const float*)d_in[0];
    const float* Wq = (const float*)d_in[1];
    const float* bq = (const float*)d_in[2];
    const float* Wk = (const float*)d_in[3];
    const float* bk = (const float*)d_in[4];
    const float* Wv = (const float*)d_in[5];
    const float* bv = (const float*)d_in[6];
    const float* Wp = (const float*)d_in[7];
    const float* bp = (const float*)d_in[8];
    float* out = (float*)d_out;

    char* ws = (char*)d_ws;
    unsigned short* xb    = (unsigned short*)(ws);                        // 16 MB
    unsigned short* wqkvt = (unsigned short*)(ws + (16u << 20));          //  6 MB
    unsigned short* wpt   = (unsigned short*)(ws + (22u << 20));          //  2 MB
    unsigned short* qbuf  = (unsigned short*)(ws + (24u << 20));          // 16 MB
    unsigned short* kbuf  = (unsigned short*)(ws + (40u << 20));          // 16 MB
    unsigned short* vtbuf = (unsigned short*)(ws + (56u << 20));          // 16 MB
    unsigned short* ybuf  = (unsigned short*)(ws + (72u << 20));          // 16 MB

    int n8 = M_ * C_ / 8;
    k_cvt_x<<<(n8 + 255) / 256, 256, 0, stream>>>(x, xb, n8);

    dim3 tb(32, 8);
    dim3 tg(32, 32);
    k_transpose_cvt<<<tg, tb, 0, stream>>>(Wq, wqkvt,                 C_, C_);
    k_transpose_cvt<<<tg, tb, 0, stream>>>(Wk, wqkvt + (1u << 20),    C_, C_);
    k_transpose_cvt<<<tg, tb, 0, stream>>>(Wv, wqkvt + (2u << 20),    C_, C_);
    k_transpose_cvt<<<tg, tb, 0, stream>>>(Wp, wpt,                   C_, C_);

    k_gemm<0><<<dim3(M_ / 64, 3 * C_ / 64), 256, 0, stream>>>(
        xb, wqkvt, bq, bk, bv, qbuf, kbuf, vtbuf, nullptr);

    k_attn<<<dim3(T_ / 64, B_ * H_), 256, 0, stream>>>(qbuf, kbuf, vtbuf, ybuf);

    k_gemm<1><<<dim3(M_ / 64, C_ / 64), 256, 0, stream>>>(
        ybuf, wpt, bp, nullptr, nullptr, nullptr, nullptr, nullptr, out);
}

// Round 2
// 370.797 us; speedup vs baseline: 1.9250x; 1.9250x over previous
//
#include <hip/hip_runtime.h>
#include <stdint.h>

#define B_  4
#define T_  2048
#define C_  1024
#define H_  16
#define HD_ 64
#define M_  (B_*T_)   // 8192

typedef __attribute__((ext_vector_type(8)))  __bf16 bf16x8;
typedef __attribute__((ext_vector_type(4)))  float  f32x4;
typedef __attribute__((ext_vector_type(16))) float  f32x16;
typedef __attribute__((ext_vector_type(4)))  unsigned int u32x4;

#define QSCALE 0.18033688011112042f   // 0.125 * log2(e): folded into Q projection

__device__ __forceinline__ unsigned short f2bf(float f) {
    union { float f; unsigned int u; } v; v.f = f;
    unsigned int r = v.u + 0x7fffu + ((v.u >> 16) & 1u);   // RNE
    return (unsigned short)(r >> 16);
}
__device__ __forceinline__ unsigned int pack2(float a, float b) {
    return (unsigned int)f2bf(a) | ((unsigned int)f2bf(b) << 16);
}
__device__ __forceinline__ void gload16(const void* g, void* l) {
    __builtin_amdgcn_global_load_lds(
        (const __attribute__((address_space(1))) unsigned int*)(uintptr_t)g,
        (__attribute__((address_space(3))) unsigned int*)(unsigned int)(uintptr_t)l,
        16, 0, 0);
}

// ---------------- f32 -> bf16 convert (x) ----------------
__global__ __launch_bounds__(256) void k_cvt_x(const float* __restrict__ x,
                                               unsigned short* __restrict__ xb, int n8) {
    int i = blockIdx.x * blockDim.x + threadIdx.x;
    if (i >= n8) return;
    const float4* p = (const float4*)x + (size_t)i * 2;
    float4 a = p[0], b = p[1];
    u32x4 o = { pack2(a.x, a.y), pack2(a.z, a.w), pack2(b.x, b.y), pack2(b.z, b.w) };
    *(u32x4*)(xb + (size_t)i * 8) = o;
}

// ------------- transpose+convert weights: src[K][N] f32 -> dst[N][K] bf16 -------------
__global__ __launch_bounds__(256) void k_transpose_cvt(const float* __restrict__ src,
                                                       unsigned short* __restrict__ dst,
                                                       int rows, int cols) {
    __shared__ float tile[32][33];
    int c0 = blockIdx.x * 32, r0 = blockIdx.y * 32;
    int tx = threadIdx.x, ty = threadIdx.y;   // (32,8)
    for (int i = 0; i < 4; i++)
        tile[ty + i * 8][tx] = src[(size_t)(r0 + ty + i * 8) * cols + c0 + tx];
    __syncthreads();
    for (int i = 0; i < 4; i++)
        dst[(size_t)(c0 + ty + i * 8) * rows + r0 + tx] = f2bf(tile[tx][ty + i * 8]);
}

// ---------------- GEMM (m97 structure): out = A[M][1024] @ Bt[N][1024]^T (+bias) ----------------
// MODE 0: N=3072 fused QKV; scatter to q(scaled)[B,H,T,hd], k[B,H,T,hd], vt[B,H,hd,T] (bf16)
// MODE 1: N=1024; out f32 [M][1024] + bias
template<int MODE>
__global__ __launch_bounds__(256) void k_gemm(
    const unsigned short* __restrict__ A,
    const unsigned short* __restrict__ Bt,
    const float* __restrict__ bias0, const float* __restrict__ bias1,
    const float* __restrict__ bias2,
    unsigned short* __restrict__ qo, unsigned short* __restrict__ ko,
    unsigned short* __restrict__ vto, float* __restrict__ outf)
{
    const int K = C_;
    __shared__ __align__(16) unsigned short As[128][32];   // 8 KB, linear (gload_lds dest)
    __shared__ __align__(16) unsigned short Bs[128][32];
    int m0 = blockIdx.x * 128, n0 = blockIdx.y * 128;
    int t = threadIdx.x, w = t >> 6, l = t & 63;
    int wm = w >> 1, wn = w & 1;
    int lg = l >> 4, lr = l & 15;

    f32x4 acc[4][4];
    for (int i = 0; i < 4; i++) for (int j = 0; j < 4; j++)
        acc[i][j] = (f32x4){0.f, 0.f, 0.f, 0.f};

    int arow = w * 16 + (l >> 2);          // + j*64
    int acol = (l & 3) * 8;
    char* asb = (char*)&As[0][0] + w * 1024 + l * 16;
    char* bsb = (char*)&Bs[0][0] + w * 1024 + l * 16;

    for (int k0 = 0; k0 < K; k0 += 32) {
        __syncthreads();                   // previous tile consumed
        #pragma unroll
        for (int j = 0; j < 2; j++) {
            gload16(A  + (size_t)(m0 + j * 64 + arow) * K + k0 + acol, asb + j * 4096);
            gload16(Bt + (size_t)(n0 + j * 64 + arow) * K + k0 + acol, bsb + j * 4096);
        }
        __syncthreads();                   // drains vmcnt(0): tile ready
        bf16x8 af[4], bfr[4];
        #pragma unroll
        for (int i = 0; i < 4; i++) af[i]  = *(const bf16x8*)(&As[wm * 64 + i * 16 + lr][lg * 8]);
        #pragma unroll
        for (int j = 0; j < 4; j++) bfr[j] = *(const bf16x8*)(&Bs[wn * 64 + j * 16 + lr][lg * 8]);
        #pragma unroll
        for (int i = 0; i < 4; i++)
            #pragma unroll
            for (int j = 0; j < 4; j++)
                acc[i][j] = __builtin_amdgcn_mfma_f32_16x16x32_bf16(af[i], bfr[j], acc[i][j], 0, 0, 0);
    }

    #pragma unroll
    for (int i = 0; i < 4; i++) {
        #pragma unroll
        for (int j = 0; j < 4; j++) {
            int mrow = m0 + wm * 64 + i * 16 + lg * 4;
            int ncol = n0 + wn * 64 + j * 16 + lr;
            if (MODE == 0) {
                int sel = ncol >> 10, nc = ncol & 1023;
                int hh = nc >> 6, dd = nc & 63;
                const float* bp = (sel == 0) ? bias0 : (sel == 1) ? bias1 : bias2;
                float bvv = bp[nc];
                for (int r = 0; r < 4; r++) {
                    int mm = mrow + r;
                    int bb = mm >> 11, tt = mm & (T_ - 1);
                    float v = acc[i][j][r] + bvv;
                    if (sel == 0)      qo[((size_t)((bb * H_ + hh) * T_) + tt) * HD_ + dd] = f2bf(v * QSCALE);
                    else if (sel == 1) ko[((size_t)((bb * H_ + hh) * T_) + tt) * HD_ + dd] = f2bf(v);
                    else               vto[((size_t)((bb * H_ + hh) * HD_) + dd) * T_ + tt] = f2bf(v);
                }
            } else {
                float bvv = bias0[ncol];
                for (int r = 0; r < 4; r++)
                    outf[(size_t)(mrow + r) * C_ + ncol] = acc[i][j][r] + bvv;
            }
        }
    }
}

// ---------------- causal flash attention, swapped-operand 32x32 structure ----------------
// grid (16, B*H), block 256 (4 waves). Wave w handles q-tile {x, 63-x, 16+x, 47-x}[w]
// (uniform per-block work). Per 32-key tile: S^T = mfma(K,Q) so lane owns q-col l&31;
// softmax in log2 domain (scale folded into Q); P->bf16 via cvt_pk + permlane32_swap;
// O^T = mfma(V^T, P^T). No block barriers, P never touches LDS.
__global__ __launch_bounds__(256) void k_attn(
    const unsigned short* __restrict__ qb,
    const unsigned short* __restrict__ kb,
    const unsigned short* __restrict__ vtb,
    unsigned short* __restrict__ yb)
{
    __shared__ __align__(16) unsigned int ot[4][32][36];   // per-wave O transpose buffer
    int bh = blockIdx.y;
    int h = bh & (H_ - 1), b = bh >> 4;
    int t = threadIdx.x, w = t >> 6, l = t & 63;
    int lq = l & 31, lh = l >> 5;
    int x = blockIdx.x;
    int qt = (w == 0) ? x : (w == 1) ? 63 - x : (w == 2) ? 16 + x : 47 - x;
    int qbase = qt * 32;

    const unsigned short* qp = qb  + (size_t)bh * T_ * HD_;
    const unsigned short* kp = kb  + (size_t)bh * T_ * HD_;
    const unsigned short* vp = vtb + (size_t)bh * HD_ * T_;

    bf16x8 qf[4];
    #pragma unroll
    for (int dc = 0; dc < 4; dc++)
        qf[dc] = *(const bf16x8*)(qp + (size_t)(qbase + lq) * HD_ + dc * 16 + lh * 8);

    f32x16 o0, o1;
    #pragma unroll
    for (int r = 0; r < 16; r++) { o0[r] = 0.f; o1[r] = 0.f; }
    float mi = -1e30f, li = 0.f;

    for (int kt = 0; kt <= qt; kt++) {
        int kbb = kt * 32;
        f32x16 st;
        #pragma unroll
        for (int r = 0; r < 16; r++) st[r] = 0.f;
        #pragma unroll
        for (int dc = 0; dc < 4; dc++) {
            bf16x8 kf = *(const bf16x8*)(kp + (size_t)(kbb + lq) * HD_ + dc * 16 + lh * 8);
            st = __builtin_amdgcn_mfma_f32_32x32x16_bf16(kf, qf[dc], st, 0, 0, 0);
        }
        if (kt == qt) {                     // diagonal tile: causal mask
            #pragma unroll
            for (int r = 0; r < 16; r++) {
                int key = (r & 3) + 8 * (r >> 2) + 4 * lh;
                if (key > lq) st[r] = -1e30f;
            }
        }
        float tmax = st[0];
        #pragma unroll
        for (int r = 1; r < 16; r++) tmax = fmaxf(tmax, st[r]);
        tmax = fmaxf(tmax, __shfl_xor(tmax, 32));
        if (!__all(tmax <= mi)) {           // defer-max: skip no-op rescales
            float mnew = fmaxf(mi, tmax);
            float fac = exp2f(mi - mnew);
            mi = mnew;
            li *= fac;
            #pragma unroll
            for (int r = 0; r < 16; r++) { o0[r] *= fac; o1[r] *= fac; }
        }
        float p[16], rs = 0.f;
        #pragma unroll
        for (int r = 0; r < 16; r++) { p[r] = exp2f(st[r] - mi); rs += p[r]; }
        rs += __shfl_xor(rs, 32);
        li += rs;

        // P^T (C-layout regs) -> PV B-frags: cvt_pk pairs + permlane32 half-swap
        unsigned int pw[8];
        #pragma unroll
        for (int kc = 0; kc < 2; kc++) {
            unsigned int a0, a1, b0, b1;
            asm("v_cvt_pk_bf16_f32 %0, %1, %2" : "=v"(a0) : "v"(p[kc*8+0]), "v"(p[kc*8+1]));
            asm("v_cvt_pk_bf16_f32 %0, %1, %2" : "=v"(a1) : "v"(p[kc*8+2]), "v"(p[kc*8+3]));
            asm("v_cvt_pk_bf16_f32 %0, %1, %2" : "=v"(b0) : "v"(p[kc*8+4]), "v"(p[kc*8+5]));
            asm("v_cvt_pk_bf16_f32 %0, %1, %2" : "=v"(b1) : "v"(p[kc*8+6]), "v"(p[kc*8+7]));
            asm volatile("v_permlane32_swap_b32 %0, %1" : "+v"(a0), "+v"(b0));
            asm volatile("v_permlane32_swap_b32 %0, %1" : "+v"(a1), "+v"(b1));
            pw[kc*4+0] = a0; pw[kc*4+1] = a1; pw[kc*4+2] = b0; pw[kc*4+3] = b1;
        }
        #pragma unroll
        for (int kc = 0; kc < 2; kc++) {
            union { u32x4 u; bf16x8 v; } pb;
            pb.u = (u32x4){pw[kc*4+0], pw[kc*4+1], pw[kc*4+2], pw[kc*4+3]};
            const unsigned short* vb0 = vp + (size_t)lq * T_ + kbb + kc * 16 + lh * 8;
            bf16x8 va0 = *(const bf16x8*)(vb0);
            bf16x8 va1 = *(const bf16x8*)(vb0 + 32 * T_);
            o0 = __builtin_amdgcn_mfma_f32_32x32x16_bf16(va0, pb.v, o0, 0, 0, 0);
            o1 = __builtin_amdgcn_mfma_f32_32x32x16_bf16(va1, pb.v, o1, 0, 0, 0);
        }
    }

    // O^T regs -> LDS transpose -> coalesced 16B stores
    float inv = 1.f / li;
    #pragma unroll
    for (int r = 0; r < 16; r += 2) {
        int dh = ((r & 3) + 8 * (r >> 2) + 4 * lh) >> 1;
        ot[w][lq][dh]      = pack2(o0[r] * inv, o0[r + 1] * inv);
        ot[w][lq][16 + dh] = pack2(o1[r] * inv, o1[r + 1] * inv);
    }
    asm volatile("s_waitcnt lgkmcnt(0)" ::: "memory");
    __builtin_amdgcn_sched_barrier(0);
    #pragma unroll
    for (int i = 0; i < 4; i++) {
        int c = i * 64 + l;
        int q = c >> 3, ch = c & 7;
        u32x4 rv = *(const u32x4*)(&ot[w][q][ch * 4]);
        *(u32x4*)(yb + (size_t)(b * T_ + qbase + q) * C_ + h * HD_ + ch * 8) = rv;
    }
}

// ---------------- launcher ----------------
extern "C" void kernel_launch(void* const* d_in, const int* in_sizes, int n_in,
                              void* d_out, int out_size, void* d_ws, size_t ws_size,
                              hipStream_t stream) {
    const float* x  = (const float*)d_in[0];
    const float* Wq = (const float*)d_in[1];
    const float* bq = (const float*)d_in[2];
    const float* Wk = (const float*)d_in[3];
    const float* bk = (const float*)d_in[4];
    const float* Wv = (const float*)d_in[5];
    const float* bv = (const float*)d_in[6];
    const float* Wp = (const float*)d_in[7];
    const float* bp = (const float*)d_in[8];
    float* out = (float*)d_out;

    char* ws = (char*)d_ws;
    unsigned short* xb    = (unsigned short*)(ws);                        // 16 MB
    unsigned short* wqkvt = (unsigned short*)(ws + (16u << 20));          //  6 MB
    unsigned short* wpt   = (unsigned short*)(ws + (22u << 20));          //  2 MB
    unsigned short* qbuf  = (unsigned short*)(ws + (24u << 20));          // 16 MB
    unsigned short* kbuf  = (unsigned short*)(ws + (40u << 20));          // 16 MB
    unsigned short* vtbuf = (unsigned short*)(ws + (56u << 20));          // 16 MB
    unsigned short* ybuf  = (unsigned short*)(ws + (72u << 20));          // 16 MB

    int n8 = M_ * C_ / 8;
    k_cvt_x<<<(n8 + 255) / 256, 256, 0, stream>>>(x, xb, n8);

    dim3 tb(32, 8);
    dim3 tg(32, 32);
    k_transpose_cvt<<<tg, tb, 0, stream>>>(Wq, wqkvt,              C_, C_);
    k_transpose_cvt<<<tg, tb, 0, stream>>>(Wk, wqkvt + (1u << 20), C_, C_);
    k_transpose_cvt<<<tg, tb, 0, stream>>>(Wv, wqkvt + (2u << 20), C_, C_);
    k_transpose_cvt<<<tg, tb, 0, stream>>>(Wp, wpt,                C_, C_);

    k_gemm<0><<<dim3(M_ / 128, 3 * C_ / 128), 256, 0, stream>>>(
        xb, wqkvt, bq, bk, bv, qbuf, kbuf, vtbuf, nullptr);

    k_attn<<<dim3(16, B_ * H_), 256, 0, stream>>>(qbuf, kbuf, vtbuf, ybuf);

    k_gemm<1><<<dim3(M_ / 128, C_ / 128), 256, 0, stream>>>(
        ybuf, wpt, bp, nullptr, nullptr, nullptr, nullptr, nullptr, out);
}

// Round 3
// 332.153 us; speedup vs baseline: 2.1490x; 1.1163x over previous
//
#include <hip/hip_runtime.h>
#include <stdint.h>

#define B_  4
#define T_  2048
#define C_  1024
#define H_  16
#define HD_ 64
#define M_  (B_*T_)   // 8192

typedef __attribute__((ext_vector_type(8)))  __bf16 bf16x8;
typedef __attribute__((ext_vector_type(4)))  float  f32x4;
typedef __attribute__((ext_vector_type(16))) float  f32x16;
typedef __attribute__((ext_vector_type(4)))  unsigned int u32x4;

#define QSCALE 0.18033688011112042f   // 0.125 * log2(e): folded into Q projection

__device__ __forceinline__ unsigned short f2bf(float f) {
    union { float f; unsigned int u; } v; v.f = f;
    unsigned int r = v.u + 0x7fffu + ((v.u >> 16) & 1u);   // RNE
    return (unsigned short)(r >> 16);
}
__device__ __forceinline__ unsigned int pack2(float a, float b) {
    return (unsigned int)f2bf(a) | ((unsigned int)f2bf(b) << 16);
}
__device__ __forceinline__ void gload16(const void* g, void* l) {
    __builtin_amdgcn_global_load_lds(
        (const __attribute__((address_space(1))) unsigned int*)(uintptr_t)g,
        (__attribute__((address_space(3))) unsigned int*)(unsigned int)(uintptr_t)l,
        16, 0, 0);
}

// ---------------- f32 -> bf16 convert (x) ----------------
__global__ __launch_bounds__(256) void k_cvt_x(const float* __restrict__ x,
                                               unsigned short* __restrict__ xb, int n8) {
    int i = blockIdx.x * blockDim.x + threadIdx.x;
    if (i >= n8) return;
    const float4* p = (const float4*)x + (size_t)i * 2;
    float4 a = p[0], b = p[1];
    u32x4 o = { pack2(a.x, a.y), pack2(a.z, a.w), pack2(b.x, b.y), pack2(b.z, b.w) };
    *(u32x4*)(xb + (size_t)i * 8) = o;
}

// ------------- transpose+convert weights: src[K][N] f32 -> dst[N][K] bf16 -------------
__global__ __launch_bounds__(256) void k_transpose_cvt(const float* __restrict__ src,
                                                       unsigned short* __restrict__ dst,
                                                       int rows, int cols) {
    __shared__ float tile[32][33];
    int c0 = blockIdx.x * 32, r0 = blockIdx.y * 32;
    int tx = threadIdx.x, ty = threadIdx.y;   // (32,8)
    for (int i = 0; i < 4; i++)
        tile[ty + i * 8][tx] = src[(size_t)(r0 + ty + i * 8) * cols + c0 + tx];
    __syncthreads();
    for (int i = 0; i < 4; i++)
        dst[(size_t)(c0 + ty + i * 8) * rows + r0 + tx] = f2bf(tile[tx][ty + i * 8]);
}

// ---------------- GEMM (m97 structure): out = A[M][1024] @ Bt[N][1024]^T (+bias) ----------------
template<int MODE>
__global__ __launch_bounds__(256) void k_gemm(
    const unsigned short* __restrict__ A,
    const unsigned short* __restrict__ Bt,
    const float* __restrict__ bias0, const float* __restrict__ bias1,
    const float* __restrict__ bias2,
    unsigned short* __restrict__ qo, unsigned short* __restrict__ ko,
    unsigned short* __restrict__ vto, float* __restrict__ outf)
{
    const int K = C_;
    __shared__ __align__(16) unsigned short As[128][32];
    __shared__ __align__(16) unsigned short Bs[128][32];
    int m0 = blockIdx.x * 128, n0 = blockIdx.y * 128;
    int t = threadIdx.x, w = t >> 6, l = t & 63;
    int wm = w >> 1, wn = w & 1;
    int lg = l >> 4, lr = l & 15;

    f32x4 acc[4][4];
    for (int i = 0; i < 4; i++) for (int j = 0; j < 4; j++)
        acc[i][j] = (f32x4){0.f, 0.f, 0.f, 0.f};

    int arow = w * 16 + (l >> 2);
    int acol = (l & 3) * 8;
    char* asb = (char*)&As[0][0] + w * 1024 + l * 16;
    char* bsb = (char*)&Bs[0][0] + w * 1024 + l * 16;

    for (int k0 = 0; k0 < K; k0 += 32) {
        __syncthreads();
        #pragma unroll
        for (int j = 0; j < 2; j++) {
            gload16(A  + (size_t)(m0 + j * 64 + arow) * K + k0 + acol, asb + j * 4096);
            gload16(Bt + (size_t)(n0 + j * 64 + arow) * K + k0 + acol, bsb + j * 4096);
        }
        __syncthreads();
        bf16x8 af[4], bfr[4];
        #pragma unroll
        for (int i = 0; i < 4; i++) af[i]  = *(const bf16x8*)(&As[wm * 64 + i * 16 + lr][lg * 8]);
        #pragma unroll
        for (int j = 0; j < 4; j++) bfr[j] = *(const bf16x8*)(&Bs[wn * 64 + j * 16 + lr][lg * 8]);
        #pragma unroll
        for (int i = 0; i < 4; i++)
            #pragma unroll
            for (int j = 0; j < 4; j++)
                acc[i][j] = __builtin_amdgcn_mfma_f32_16x16x32_bf16(af[i], bfr[j], acc[i][j], 0, 0, 0);
    }

    #pragma unroll
    for (int i = 0; i < 4; i++) {
        #pragma unroll
        for (int j = 0; j < 4; j++) {
            int mrow = m0 + wm * 64 + i * 16 + lg * 4;
            int ncol = n0 + wn * 64 + j * 16 + lr;
            if (MODE == 0) {
                int sel = ncol >> 10, nc = ncol & 1023;
                int hh = nc >> 6, dd = nc & 63;
                const float* bp = (sel == 0) ? bias0 : (sel == 1) ? bias1 : bias2;
                float bvv = bp[nc];
                for (int r = 0; r < 4; r++) {
                    int mm = mrow + r;
                    int bb = mm >> 11, tt = mm & (T_ - 1);
                    float v = acc[i][j][r] + bvv;
                    if (sel == 0)      qo[((size_t)((bb * H_ + hh) * T_) + tt) * HD_ + dd] = f2bf(v * QSCALE);
                    else if (sel == 1) ko[((size_t)((bb * H_ + hh) * T_) + tt) * HD_ + dd] = f2bf(v);
                    else               vto[((size_t)((bb * H_ + hh) * HD_) + dd) * T_ + tt] = f2bf(v);
                }
            } else {
                float bvv = bias0[ncol];
                for (int r = 0; r < 4; r++)
                    outf[(size_t)(mrow + r) * C_ + ncol] = acc[i][j][r] + bvv;
            }
        }
    }
}

// ---------------- attention helpers ----------------
__device__ __forceinline__ void sm_pack(f32x16& st, bool mask, int lq, int lh,
                                        float& mi, float& li, f32x16& o0, f32x16& o1,
                                        unsigned int* pw)
{
    if (mask) {
        #pragma unroll
        for (int r = 0; r < 16; r++) {
            int key = (r & 3) + 8 * (r >> 2) + 4 * lh;
            if (key > lq) st[r] = -1e30f;
        }
    }
    float tm[8];
    #pragma unroll
    for (int i = 0; i < 8; i++) tm[i] = fmaxf(st[2 * i], st[2 * i + 1]);
    #pragma unroll
    for (int i = 0; i < 4; i++) tm[i] = fmaxf(tm[i], tm[i + 4]);
    float tmax = fmaxf(fmaxf(tm[0], tm[2]), fmaxf(tm[1], tm[3]));
    tmax = fmaxf(tmax, __shfl_xor(tmax, 32));
    if (!__all(tmax <= mi)) {               // defer-max: skip no-op rescales
        float mnew = fmaxf(mi, tmax);
        float fac = exp2f(mi - mnew);
        mi = mnew;
        li *= fac;
        #pragma unroll
        for (int r = 0; r < 16; r++) { o0[r] *= fac; o1[r] *= fac; }
    }
    #pragma unroll
    for (int r = 0; r < 16; r++) st[r] = exp2f(st[r] - mi);
    float rsum[8];
    #pragma unroll
    for (int i = 0; i < 8; i++) rsum[i] = st[2 * i] + st[2 * i + 1];
    #pragma unroll
    for (int i = 0; i < 4; i++) rsum[i] += rsum[i + 4];
    float rs = (rsum[0] + rsum[2]) + (rsum[1] + rsum[3]);
    rs += __shfl_xor(rs, 32);
    li += rs;
    #pragma unroll
    for (int kc = 0; kc < 2; kc++) {
        unsigned int a0, a1, b0, b1;
        asm("v_cvt_pk_bf16_f32 %0, %1, %2" : "=v"(a0) : "v"(st[kc*8+0]), "v"(st[kc*8+1]));
        asm("v_cvt_pk_bf16_f32 %0, %1, %2" : "=v"(a1) : "v"(st[kc*8+2]), "v"(st[kc*8+3]));
        asm("v_cvt_pk_bf16_f32 %0, %1, %2" : "=v"(b0) : "v"(st[kc*8+4]), "v"(st[kc*8+5]));
        asm("v_cvt_pk_bf16_f32 %0, %1, %2" : "=v"(b1) : "v"(st[kc*8+6]), "v"(st[kc*8+7]));
        asm volatile("v_permlane32_swap_b32 %0, %1" : "+v"(a0), "+v"(b0));
        asm volatile("v_permlane32_swap_b32 %0, %1" : "+v"(a1), "+v"(b1));
        pw[kc*4+0] = a0; pw[kc*4+1] = a1; pw[kc*4+2] = b0; pw[kc*4+3] = b1;
    }
}

__device__ __forceinline__ void pv_step(const unsigned int* pw, const bf16x8* vc,
                                        f32x16& o0, f32x16& o1)
{
    #pragma unroll
    for (int kc = 0; kc < 2; kc++) {
        union { u32x4 u; bf16x8 v; } pb;
        pb.u = (u32x4){pw[kc*4+0], pw[kc*4+1], pw[kc*4+2], pw[kc*4+3]};
        o0 = __builtin_amdgcn_mfma_f32_32x32x16_bf16(vc[kc*2],     pb.v, o0, 0, 0, 0);
        o1 = __builtin_amdgcn_mfma_f32_32x32x16_bf16(vc[kc*2 + 1], pb.v, o1, 0, 0, 0);
    }
}

__device__ __forceinline__ void attn_writeout(unsigned int (*otw)[36],
                                              const f32x16& o0, const f32x16& o1, float li,
                                              int lq, int lh, int l,
                                              unsigned short* dst)
{
    float inv = 1.f / li;
    #pragma unroll
    for (int r = 0; r < 16; r += 2) {
        int dh = ((r & 3) + 8 * (r >> 2) + 4 * lh) >> 1;
        otw[lq][dh]      = pack2(o0[r] * inv, o0[r + 1] * inv);
        otw[lq][16 + dh] = pack2(o1[r] * inv, o1[r + 1] * inv);
    }
    asm volatile("s_waitcnt lgkmcnt(0)" ::: "memory");
    __builtin_amdgcn_sched_barrier(0);
    #pragma unroll
    for (int i = 0; i < 4; i++) {
        int c = i * 64 + l;
        int q = c >> 3, ch = c & 7;
        u32x4 rv = *(const u32x4*)(&otw[q][ch * 4]);
        *(u32x4*)(dst + (size_t)q * C_ + ch * 8) = rv;
    }
}

// ---------------- causal flash attention, paired q-tiles ----------------
// grid (8, B*H), block 256 (4 waves). Wave x = bx*4+w handles q-tiles (x, 63-x):
// uniform 65 tile-computations per wave; K/V loaded ONCE per key-tile and shared by
// both q-tiles in the dual region; two independent MFMA/softmax chains for ILP.
__global__ __launch_bounds__(256) void k_attn(
    const unsigned short* __restrict__ qb,
    const unsigned short* __restrict__ kb,
    const unsigned short* __restrict__ vtb,
    unsigned short* __restrict__ yb)
{
    __shared__ __align__(16) unsigned int ot[4][2][32][36];
    int bh = blockIdx.y;
    int h = bh & (H_ - 1), b = bh >> 4;
    int t = threadIdx.x, w = t >> 6, l = t & 63;
    int lq = l & 31, lh = l >> 5;
    int x = blockIdx.x * 4 + w;            // 0..31
    int qtA = x, qtB = 63 - x;
    int qbA = qtA * 32, qbB = qtB * 32;

    const unsigned short* qp = qb  + (size_t)bh * T_ * HD_;
    const unsigned short* kp = kb  + (size_t)bh * T_ * HD_;
    const unsigned short* vp = vtb + (size_t)bh * HD_ * T_;

    bf16x8 qA[4], qB[4];
    #pragma unroll
    for (int dc = 0; dc < 4; dc++) {
        qA[dc] = *(const bf16x8*)(qp + (size_t)(qbA + lq) * HD_ + dc * 16 + lh * 8);
        qB[dc] = *(const bf16x8*)(qp + (size_t)(qbB + lq) * HD_ + dc * 16 + lh * 8);
    }

    f32x16 oA0, oA1, oB0, oB1;
    #pragma unroll
    for (int r = 0; r < 16; r++) { oA0[r] = 0.f; oA1[r] = 0.f; oB0[r] = 0.f; oB1[r] = 0.f; }
    float miA = -1e30f, liA = 0.f, miB = -1e30f, liB = 0.f;

    bf16x8 kc[4];
    #pragma unroll
    for (int dc = 0; dc < 4; dc++)
        kc[dc] = *(const bf16x8*)(kp + (size_t)lq * HD_ + dc * 16 + lh * 8);

    int kt = 0;
    // ---- dual region: kt = 0..qtA (both q-tiles consume this key-tile) ----
    for (; kt <= qtA; ++kt) {
        int kbb = kt * 32;
        const unsigned short* vb = vp + (size_t)lq * T_ + kbb + lh * 8;
        bf16x8 vc[4];
        vc[0] = *(const bf16x8*)(vb);
        vc[1] = *(const bf16x8*)(vb + 32 * T_);
        vc[2] = *(const bf16x8*)(vb + 16);
        vc[3] = *(const bf16x8*)(vb + 16 + 32 * T_);
        const unsigned short* kr = kp + (size_t)(kbb + 32 + lq) * HD_ + lh * 8;   // kt+1 <= qtB always here
        bf16x8 kn[4];
        #pragma unroll
        for (int dc = 0; dc < 4; dc++) kn[dc] = *(const bf16x8*)(kr + dc * 16);

        f32x16 stA, stB;
        #pragma unroll
        for (int r = 0; r < 16; r++) { stA[r] = 0.f; stB[r] = 0.f; }
        #pragma unroll
        for (int dc = 0; dc < 4; dc++) {
            stB = __builtin_amdgcn_mfma_f32_32x32x16_bf16(kc[dc], qB[dc], stB, 0, 0, 0);
            stA = __builtin_amdgcn_mfma_f32_32x32x16_bf16(kc[dc], qA[dc], stA, 0, 0, 0);
        }
        unsigned int pwA[8], pwB[8];
        sm_pack(stB, false,       lq, lh, miB, liB, oB0, oB1, pwB);
        sm_pack(stA, (kt == qtA), lq, lh, miA, liA, oA0, oA1, pwA);
        pv_step(pwB, vc, oB0, oB1);
        pv_step(pwA, vc, oA0, oA1);
        #pragma unroll
        for (int dc = 0; dc < 4; dc++) kc[dc] = kn[dc];
    }
    // ---- single region: kt = qtA+1..qtB (only q-tile B) ----
    for (; kt <= qtB; ++kt) {
        int kbb = kt * 32;
        const unsigned short* vb = vp + (size_t)lq * T_ + kbb + lh * 8;
        bf16x8 vc[4];
        vc[0] = *(const bf16x8*)(vb);
        vc[1] = *(const bf16x8*)(vb + 32 * T_);
        vc[2] = *(const bf16x8*)(vb + 16);
        vc[3] = *(const bf16x8*)(vb + 16 + 32 * T_);
        int knext = (kt < qtB) ? (kbb + 32) : kbb;       // clamp: avoid OOB, stay uniform
        const unsigned short* kr = kp + (size_t)(knext + lq) * HD_ + lh * 8;
        bf16x8 kn[4];
        #pragma unroll
        for (int dc = 0; dc < 4; dc++) kn[dc] = *(const bf16x8*)(kr + dc * 16);

        f32x16 stB;
        #pragma unroll
        for (int r = 0; r < 16; r++) stB[r] = 0.f;
        #pragma unroll
        for (int dc = 0; dc < 4; dc++)
            stB = __builtin_amdgcn_mfma_f32_32x32x16_bf16(kc[dc], qB[dc], stB, 0, 0, 0);
        unsigned int pwB[8];
        sm_pack(stB, (kt == qtB), lq, lh, miB, liB, oB0, oB1, pwB);
        pv_step(pwB, vc, oB0, oB1);
        #pragma unroll
        for (int dc = 0; dc < 4; dc++) kc[dc] = kn[dc];
    }

    unsigned short* dstA = yb + (size_t)(b * T_ + qbA) * C_ + h * HD_;
    unsigned short* dstB = yb + (size_t)(b * T_ + qbB) * C_ + h * HD_;
    attn_writeout(ot[w][0], oA0, oA1, liA, lq, lh, l, dstA);
    attn_writeout(ot[w][1], oB0, oB1, liB, lq, lh, l, dstB);
}

// ---------------- launcher ----------------
extern "C" void kernel_launch(void* const* d_in, const int* in_sizes, int n_in,
                              void* d_out, int out_size, void* d_ws, size_t ws_size,
                              hipStream_t stream) {
    const float* x  = (const float*)d_in[0];
    const float* Wq = (const float*)d_in[1];
    const float* bq = (const float*)d_in[2];
    const float* Wk = (const float*)d_in[3];
    const float* bk = (const float*)d_in[4];
    const float* Wv = (const float*)d_in[5];
    const float* bv = (const float*)d_in[6];
    const float* Wp = (const float*)d_in[7];
    const float* bp = (const float*)d_in[8];
    float* out = (float*)d_out;

    char* ws = (char*)d_ws;
    unsigned short* xb    = (unsigned short*)(ws);                        // 16 MB
    unsigned short* wqkvt = (unsigned short*)(ws + (16u << 20));          //  6 MB
    unsigned short* wpt   = (unsigned short*)(ws + (22u << 20));          //  2 MB
    unsigned short* qbuf  = (unsigned short*)(ws + (24u << 20));          // 16 MB
    unsigned short* kbuf  = (unsigned short*)(ws + (40u << 20));          // 16 MB
    unsigned short* vtbuf = (unsigned short*)(ws + (56u << 20));          // 16 MB
    unsigned short* ybuf  = (unsigned short*)(ws + (72u << 20));          // 16 MB

    int n8 = M_ * C_ / 8;
    k_cvt_x<<<(n8 + 255) / 256, 256, 0, stream>>>(x, xb, n8);

    dim3 tb(32, 8);
    dim3 tg(32, 32);
    k_transpose_cvt<<<tg, tb, 0, stream>>>(Wq, wqkvt,              C_, C_);
    k_transpose_cvt<<<tg, tb, 0, stream>>>(Wk, wqkvt + (1u << 20), C_, C_);
    k_transpose_cvt<<<tg, tb, 0, stream>>>(Wv, wqkvt + (2u << 20), C_, C_);
    k_transpose_cvt<<<tg, tb, 0, stream>>>(Wp, wpt,                C_, C_);

    k_gemm<0><<<dim3(M_ / 128, 3 * C_ / 128), 256, 0, stream>>>(
        xb, wqkvt, bq, bk, bv, qbuf, kbuf, vtbuf, nullptr);

    k_attn<<<dim3(8, B_ * H_), 256, 0, stream>>>(qbuf, kbuf, vtbuf, ybuf);

    k_gemm<1><<<dim3(M_ / 128, C_ / 128), 256, 0, stream>>>(
        ybuf, wpt, bp, nullptr, nullptr, nullptr, nullptr, nullptr, out);
}

// Round 5
// 290.782 us; speedup vs baseline: 2.4547x; 1.1423x over previous
//
#include <hip/hip_runtime.h>
#include <stdint.h>

#define B_  4
#define T_  2048
#define C_  1024
#define H_  16
#define HD_ 64
#define M_  (B_*T_)   // 8192

typedef __attribute__((ext_vector_type(8)))  __bf16 bf16x8;
typedef __attribute__((ext_vector_type(4)))  float  f32x4;
typedef __attribute__((ext_vector_type(16))) float  f32x16;
typedef __attribute__((ext_vector_type(4)))  unsigned int u32x4;

#define QSCALE 0.18033688011112042f   // 0.125 * log2(e): folded into Q projection

__device__ __forceinline__ unsigned short f2bf(float f) {
    union { float f; unsigned int u; } v; v.f = f;
    unsigned int r = v.u + 0x7fffu + ((v.u >> 16) & 1u);   // RNE
    return (unsigned short)(r >> 16);
}
__device__ __forceinline__ unsigned int pack2(float a, float b) {
    return (unsigned int)f2bf(a) | ((unsigned int)f2bf(b) << 16);
}
__device__ __forceinline__ void gload16(const void* g, void* l) {
    __builtin_amdgcn_global_load_lds(
        (const __attribute__((address_space(1))) unsigned int*)(uintptr_t)g,
        (__attribute__((address_space(3))) unsigned int*)(unsigned int)(uintptr_t)l,
        16, 0, 0);
}

// ---------------- f32 -> bf16 convert (x) ----------------
__global__ __launch_bounds__(256) void k_cvt_x(const float* __restrict__ x,
                                               unsigned short* __restrict__ xb, int n8) {
    int i = blockIdx.x * blockDim.x + threadIdx.x;
    if (i >= n8) return;
    const float4* p = (const float4*)x + (size_t)i * 2;
    float4 a = p[0], b = p[1];
    u32x4 o = { pack2(a.x, a.y), pack2(a.z, a.w), pack2(b.x, b.y), pack2(b.z, b.w) };
    *(u32x4*)(xb + (size_t)i * 8) = o;
}

// ------------- transpose+convert weights: src[K][N] f32 -> dst[N][K] bf16 -------------
__global__ __launch_bounds__(256) void k_transpose_cvt(const float* __restrict__ src,
                                                       unsigned short* __restrict__ dst,
                                                       int rows, int cols) {
    __shared__ float tile[32][33];
    int c0 = blockIdx.x * 32, r0 = blockIdx.y * 32;
    int tx = threadIdx.x, ty = threadIdx.y;   // (32,8)
    for (int i = 0; i < 4; i++)
        tile[ty + i * 8][tx] = src[(size_t)(r0 + ty + i * 8) * cols + c0 + tx];
    __syncthreads();
    for (int i = 0; i < 4; i++)
        dst[(size_t)(c0 + ty + i * 8) * rows + r0 + tx] = f2bf(tile[tx][ty + i * 8]);
}

// ---------------- GEMM (m97 structure): out = A[M][1024] @ Bt[N][1024]^T (+bias) ----------------
template<int MODE>
__global__ __launch_bounds__(256) void k_gemm(
    const unsigned short* __restrict__ A,
    const unsigned short* __restrict__ Bt,
    const float* __restrict__ bias0, const float* __restrict__ bias1,
    const float* __restrict__ bias2,
    unsigned short* __restrict__ qo, unsigned short* __restrict__ ko,
    unsigned short* __restrict__ vto, float* __restrict__ outf)
{
    const int K = C_;
    __shared__ __align__(16) unsigned short As[128][32];
    __shared__ __align__(16) unsigned short Bs[128][32];
    int m0 = blockIdx.x * 128, n0 = blockIdx.y * 128;
    int t = threadIdx.x, w = t >> 6, l = t & 63;
    int wm = w >> 1, wn = w & 1;
    int lg = l >> 4, lr = l & 15;

    f32x4 acc[4][4];
    for (int i = 0; i < 4; i++) for (int j = 0; j < 4; j++)
        acc[i][j] = (f32x4){0.f, 0.f, 0.f, 0.f};

    int arow = w * 16 + (l >> 2);
    int acol = (l & 3) * 8;
    char* asb = (char*)&As[0][0] + w * 1024 + l * 16;
    char* bsb = (char*)&Bs[0][0] + w * 1024 + l * 16;

    for (int k0 = 0; k0 < K; k0 += 32) {
        __syncthreads();
        #pragma unroll
        for (int j = 0; j < 2; j++) {
            gload16(A  + (size_t)(m0 + j * 64 + arow) * K + k0 + acol, asb + j * 4096);
            gload16(Bt + (size_t)(n0 + j * 64 + arow) * K + k0 + acol, bsb + j * 4096);
        }
        __syncthreads();
        bf16x8 af[4], bfr[4];
        #pragma unroll
        for (int i = 0; i < 4; i++) af[i]  = *(const bf16x8*)(&As[wm * 64 + i * 16 + lr][lg * 8]);
        #pragma unroll
        for (int j = 0; j < 4; j++) bfr[j] = *(const bf16x8*)(&Bs[wn * 64 + j * 16 + lr][lg * 8]);
        #pragma unroll
        for (int i = 0; i < 4; i++)
            #pragma unroll
            for (int j = 0; j < 4; j++)
                acc[i][j] = __builtin_amdgcn_mfma_f32_16x16x32_bf16(af[i], bfr[j], acc[i][j], 0, 0, 0);
    }

    #pragma unroll
    for (int i = 0; i < 4; i++) {
        #pragma unroll
        for (int j = 0; j < 4; j++) {
            int mrow = m0 + wm * 64 + i * 16 + lg * 4;
            int ncol = n0 + wn * 64 + j * 16 + lr;
            if (MODE == 0) {
                int sel = ncol >> 10, nc = ncol & 1023;
                int hh = nc >> 6, dd = nc & 63;
                const float* bp = (sel == 0) ? bias0 : (sel == 1) ? bias1 : bias2;
                float bvv = bp[nc];
                for (int r = 0; r < 4; r++) {
                    int mm = mrow + r;
                    int bb = mm >> 11, tt = mm & (T_ - 1);
                    float v = acc[i][j][r] + bvv;
                    if (sel == 0)      qo[((size_t)((bb * H_ + hh) * T_) + tt) * HD_ + dd] = f2bf(v * QSCALE);
                    else if (sel == 1) ko[((size_t)((bb * H_ + hh) * T_) + tt) * HD_ + dd] = f2bf(v);
                    else               vto[((size_t)((bb * H_ + hh) * HD_) + dd) * T_ + tt] = f2bf(v);
                }
            } else {
                float bvv = bias0[ncol];
                for (int r = 0; r < 4; r++)
                    outf[(size_t)(mrow + r) * C_ + ncol] = acc[i][j][r] + bvv;
            }
        }
    }
}

// ---------------- attention helpers ----------------
__device__ __forceinline__ void sm_pack(f32x16& st, bool mask, int lq, int lh,
                                        float& mi, float& li, f32x16& o0, f32x16& o1,
                                        unsigned int* pw)
{
    if (mask) {
        #pragma unroll
        for (int r = 0; r < 16; r++) {
            int key = (r & 3) + 8 * (r >> 2) + 4 * lh;
            if (key > lq) st[r] = -1e30f;
        }
    }
    float tm[8];
    #pragma unroll
    for (int i = 0; i < 8; i++) tm[i] = fmaxf(st[2 * i], st[2 * i + 1]);
    #pragma unroll
    for (int i = 0; i < 4; i++) tm[i] = fmaxf(tm[i], tm[i + 4]);
    float tmax = fmaxf(fmaxf(tm[0], tm[2]), fmaxf(tm[1], tm[3]));
    tmax = fmaxf(tmax, __shfl_xor(tmax, 32));
    if (!__all(tmax <= mi)) {               // defer-max: mi starts at 12 -> rarely taken
        float mnew = fmaxf(mi, tmax);
        float fac = exp2f(mi - mnew);
        mi = mnew;
        li *= fac;
        #pragma unroll
        for (int r = 0; r < 16; r++) { o0[r] *= fac; o1[r] *= fac; }
    }
    #pragma unroll
    for (int r = 0; r < 16; r++) st[r] = exp2f(st[r] - mi);
    float rsum[8];
    #pragma unroll
    for (int i = 0; i < 8; i++) rsum[i] = st[2 * i] + st[2 * i + 1];
    #pragma unroll
    for (int i = 0; i < 4; i++) rsum[i] += rsum[i + 4];
    float rs = (rsum[0] + rsum[2]) + (rsum[1] + rsum[3]);
    rs += __shfl_xor(rs, 32);
    li += rs;
    #pragma unroll
    for (int kc = 0; kc < 2; kc++) {
        unsigned int a0, a1, b0, b1;
        asm("v_cvt_pk_bf16_f32 %0, %1, %2" : "=v"(a0) : "v"(st[kc*8+0]), "v"(st[kc*8+1]));
        asm("v_cvt_pk_bf16_f32 %0, %1, %2" : "=v"(a1) : "v"(st[kc*8+2]), "v"(st[kc*8+3]));
        asm("v_cvt_pk_bf16_f32 %0, %1, %2" : "=v"(b0) : "v"(st[kc*8+4]), "v"(st[kc*8+5]));
        asm("v_cvt_pk_bf16_f32 %0, %1, %2" : "=v"(b1) : "v"(st[kc*8+6]), "v"(st[kc*8+7]));
        asm volatile("v_permlane32_swap_b32 %0, %1" : "+v"(a0), "+v"(b0));
        asm volatile("v_permlane32_swap_b32 %0, %1" : "+v"(a1), "+v"(b1));
        pw[kc*4+0] = a0; pw[kc*4+1] = a1; pw[kc*4+2] = b0; pw[kc*4+3] = b1;
    }
}

__device__ __forceinline__ void pv_step(const unsigned int* pw, const bf16x8* vc,
                                        f32x16& o0, f32x16& o1)
{
    #pragma unroll
    for (int kc = 0; kc < 2; kc++) {
        union { u32x4 u; bf16x8 v; } pb;
        pb.u = (u32x4){pw[kc*4+0], pw[kc*4+1], pw[kc*4+2], pw[kc*4+3]};
        o0 = __builtin_amdgcn_mfma_f32_32x32x16_bf16(vc[kc*2],     pb.v, o0, 0, 0, 0);
        o1 = __builtin_amdgcn_mfma_f32_32x32x16_bf16(vc[kc*2 + 1], pb.v, o1, 0, 0, 0);
    }
}

__device__ __forceinline__ void attn_writeout(unsigned int (*otw)[36],
                                              const f32x16& o0, const f32x16& o1, float li,
                                              int lq, int lh, int l,
                                              unsigned short* dst)
{
    float inv = 1.f / li;
    #pragma unroll
    for (int r = 0; r < 16; r += 2) {
        int dh = ((r & 3) + 8 * (r >> 2) + 4 * lh) >> 1;
        otw[lq][dh]      = pack2(o0[r] * inv, o0[r + 1] * inv);
        otw[lq][16 + dh] = pack2(o1[r] * inv, o1[r + 1] * inv);
    }
    asm volatile("s_waitcnt lgkmcnt(0)" ::: "memory");
    __builtin_amdgcn_sched_barrier(0);
    #pragma unroll
    for (int i = 0; i < 4; i++) {
        int c = i * 64 + l;
        int q = c >> 3, ch = c & 7;
        u32x4 rv = *(const u32x4*)(&otw[q][ch * 4]);
        *(u32x4*)(dst + (size_t)q * C_ + ch * 8) = rv;
    }
}

// Stage one 64-key K tile (8KB) + V^T tile (8KB) into LDS, XOR-swizzled source
// (rule 21: linear gload_lds dest + pre-swizzled global src + swizzled read).
__device__ __forceinline__ void stage_kv(const unsigned short* kp, const unsigned short* vp,
                                         char* lds, int kt, int tid)
{
    int r = tid >> 3, sl = tid & 7;
    #pragma unroll
    for (int c = 0; c < 2; c++) {
        int row = c * 32 + r;
        gload16(kp + ((size_t)(kt * 64 + row)) * HD_ + ((sl ^ (row & 7)) * 8),
                lds + c * 4096 + tid * 16);
    }
    #pragma unroll
    for (int c = 0; c < 2; c++) {
        int d = c * 32 + r;
        gload16(vp + (size_t)d * T_ + kt * 64 + ((sl ^ (d & 7)) * 8),
                lds + 8192 + c * 4096 + tid * 16);
    }
}

// ---------------- causal flash attention, paired q-tiles + block LDS staging ----------------
// grid (64 bh, 8 x), block 256 (4 waves). Wave w owns q-tile pair (p, 63-p), p = 4x+w.
// Block cooperatively double-buffers 64-key K/V tiles in LDS (staged ONCE, used by all
// 4 waves and both q-tiles). Counted vmcnt(4) keeps next tile's loads in flight.
__global__ __launch_bounds__(256, 2) void k_attn(
    const unsigned short* __restrict__ qb,
    const unsigned short* __restrict__ kb,
    const unsigned short* __restrict__ vtb,
    unsigned short* __restrict__ yb)
{
    __shared__ __align__(16) char smem[32768];   // 2 x (K 8KB + V 8KB); reused for writeout
    int bh = blockIdx.x;                          // head-major: all 8 blocks of a bh on one XCD
    int x  = blockIdx.y;
    int h = bh & (H_ - 1), b = bh >> 4;
    int tid = threadIdx.x, w = tid >> 6, l = tid & 63;
    int lq = l & 31, lh = l >> 5;
    int p = x * 4 + w;                            // pair 0..31
    int qtA = p, qtB = 63 - p;                    // qtA < qtB always
    int qbA = qtA * 32, qbB = qtB * 32;
    int nt = 32 - 2 * x;                          // 64-key tiles staged by this block (even, >=18)

    const unsigned short* qp = qb  + (size_t)bh * T_ * HD_;
    const unsigned short* kp = kb  + (size_t)bh * T_ * HD_;
    const unsigned short* vp = vtb + (size_t)bh * HD_ * T_;

    bf16x8 qA[4], qB[4];
    #pragma unroll
    for (int dc = 0; dc < 4; dc++) {
        qA[dc] = *(const bf16x8*)(qp + (size_t)(qbA + lq) * HD_ + dc * 16 + lh * 8);
        qB[dc] = *(const bf16x8*)(qp + (size_t)(qbB + lq) * HD_ + dc * 16 + lh * 8);
    }

    f32x16 oA0, oA1, oB0, oB1;
    #pragma unroll
    for (int r = 0; r < 16; r++) { oA0[r] = 0.f; oA1[r] = 0.f; oB0[r] = 0.f; oB1[r] = 0.f; }
    float miA = 12.f, liA = 0.f, miB = 12.f, liB = 0.f;   // high init: rescale ~never fires

    stage_kv(kp, vp, smem,         0, tid);
    stage_kv(kp, vp, smem + 16384, 1, tid);

    for (int t = 0; t < nt; t++) {
        if (t < nt - 1) asm volatile("s_waitcnt vmcnt(4)" ::: "memory");
        else            asm volatile("s_waitcnt vmcnt(0)" ::: "memory");
        __builtin_amdgcn_s_barrier();
        __builtin_amdgcn_sched_barrier(0);
        const unsigned short* Kb = (const unsigned short*)(smem + (t & 1) * 16384);
        const unsigned short* Vb = Kb + 4096;

        #pragma unroll
        for (int s = 0; s < 2; s++) {
            int kt32 = 2 * t + s;
            if (kt32 > qtB) break;
            bool doA = (kt32 <= qtA);

            bf16x8 kc[4], vc[4];
            #pragma unroll
            for (int dc = 0; dc < 4; dc++) {
                int row = s * 32 + lq;
                kc[dc] = *(const bf16x8*)(Kb + row * 64 + (((dc * 2 + lh) ^ (row & 7)) * 8));
            }
            #pragma unroll
            for (int vi = 0; vi < 4; vi++) {
                int d = lq + (vi & 1) * 32;
                int slot = (s * 4 + (vi >> 1) * 2 + lh) ^ (d & 7);
                vc[vi] = *(const bf16x8*)(Vb + d * 64 + slot * 8);
            }

            f32x16 stA, stB;
            #pragma unroll
            for (int r = 0; r < 16; r++) { stA[r] = 0.f; stB[r] = 0.f; }
            __builtin_amdgcn_s_setprio(1);
            #pragma unroll
            for (int dc = 0; dc < 4; dc++) {
                stB = __builtin_amdgcn_mfma_f32_32x32x16_bf16(kc[dc], qB[dc], stB, 0, 0, 0);
                if (doA)
                    stA = __builtin_amdgcn_mfma_f32_32x32x16_bf16(kc[dc], qA[dc], stA, 0, 0, 0);
            }
            __builtin_amdgcn_s_setprio(0);

            unsigned int pwA[8], pwB[8];
            sm_pack(stB, (kt32 == qtB), lq, lh, miB, liB, oB0, oB1, pwB);
            if (doA) sm_pack(stA, (kt32 == qtA), lq, lh, miA, liA, oA0, oA1, pwA);
            __builtin_amdgcn_s_setprio(1);
            pv_step(pwB, vc, oB0, oB1);
            if (doA) pv_step(pwA, vc, oA0, oA1);
            __builtin_amdgcn_s_setprio(0);
        }

        __builtin_amdgcn_s_barrier();
        __builtin_amdgcn_sched_barrier(0);
        if (t + 2 < nt) stage_kv(kp, vp, smem + (t & 1) * 16384, t + 2, tid);
    }

    // all staging drained (vmcnt(0) on last iter) and all waves past final barrier:
    // reuse staging LDS for the output transpose
    unsigned int (*otw)[36] = (unsigned int (*)[36])(smem + w * 4608);
    unsigned short* dstA = yb + (size_t)(b * T_ + qbA) * C_ + h * HD_;
    unsigned short* dstB = yb + (size_t)(b * T_ + qbB) * C_ + h * HD_;
    attn_writeout(otw, oA0, oA1, liA, lq, lh, l, dstA);
    attn_writeout(otw, oB0, oB1, liB, lq, lh, l, dstB);
}

// ---------------- launcher ----------------
extern "C" void kernel_launch(void* const* d_in, const int* in_sizes, int n_in,
                              void* d_out, int out_size, void* d_ws, size_t ws_size,
                              hipStream_t stream) {
    const float* x  = (const float*)d_in[0];
    const float* Wq = (const float*)d_in[1];
    const float* bq = (const float*)d_in[2];
    const float* Wk = (const float*)d_in[3];
    const float* bk = (const float*)d_in[4];
    const float* Wv = (const float*)d_in[5];
    const float* bv = (const float*)d_in[6];
    const float* Wp = (const float*)d_in[7];
    const float* bp = (const float*)d_in[8];
    float* out = (float*)d_out;

    char* ws = (char*)d_ws;
    unsigned short* xb    = (unsigned short*)(ws);                        // 16 MB
    unsigned short* wqkvt = (unsigned short*)(ws + (16u << 20));          //  6 MB
    unsigned short* wpt   = (unsigned short*)(ws + (22u << 20));          //  2 MB
    unsigned short* qbuf  = (unsigned short*)(ws + (24u << 20));          // 16 MB
    unsigned short* kbuf  = (unsigned short*)(ws + (40u << 20));          // 16 MB
    unsigned short* vtbuf = (unsigned short*)(ws + (56u << 20));          // 16 MB
    unsigned short* ybuf  = (unsigned short*)(ws + (72u << 20));          // 16 MB

    int n8 = M_ * C_ / 8;
    k_cvt_x<<<(n8 + 255) / 256, 256, 0, stream>>>(x, xb, n8);

    dim3 tb(32, 8);
    dim3 tg(32, 32);
    k_transpose_cvt<<<tg, tb, 0, stream>>>(Wq, wqkvt,              C_, C_);
    k_transpose_cvt<<<tg, tb, 0, stream>>>(Wk, wqkvt + (1u << 20), C_, C_);
    k_transpose_cvt<<<tg, tb, 0, stream>>>(Wv, wqkvt + (2u << 20), C_, C_);
    k_transpose_cvt<<<tg, tb, 0, stream>>>(Wp, wpt,                C_, C_);

    k_gemm<0><<<dim3(M_ / 128, 3 * C_ / 128), 256, 0, stream>>>(
        xb, wqkvt, bq, bk, bv, qbuf, kbuf, vtbuf, nullptr);

    k_attn<<<dim3(64, 8), 256, 0, stream>>>(qbuf, kbuf, vtbuf, ybuf);

    k_gemm<1><<<dim3(M_ / 128, C_ / 128), 256, 0, stream>>>(
        ybuf, wpt, bp, nullptr, nullptr, nullptr, nullptr, nullptr, out);
}